// Round 18
// baseline (54.915 us; speedup 1.0000x reference)
//
#include <hip/hip_runtime.h>
#include <math.h>

#define H 64
#define W 64
#define C 256
#define NB 2
#define SS 32
#define HW (H*W)

typedef __attribute__((ext_vector_type(2))) _Float16 half2v;
typedef __attribute__((ext_vector_type(2))) __fp16   fp16x2;

__device__ __forceinline__ half2v pk2(float a) {
  return __builtin_bit_cast(half2v, __builtin_amdgcn_cvt_pkrtz(a, a));
}

__device__ __forceinline__ float fdot2(half2v a, half2v b, float c) {
#if __has_builtin(__builtin_amdgcn_fdot2)
  return __builtin_amdgcn_fdot2(__builtin_bit_cast(fp16x2, a),
                                __builtin_bit_cast(fp16x2, b), c, false);
#else
  c = fmaf((float)a.x, (float)b.x, c);
  c = fmaf((float)a.y, (float)b.y, c);
  return c;
#endif
}

// ---- fmat body (fp64) ----
__device__ void fmat_compute(const float* __restrict__ P1f,
                             const float* __restrict__ P2f,
                             double* __restrict__ Fout, int n) {
  double p1[3][4], p2[3][4];
  for (int i = 0; i < 3; ++i)
    for (int j = 0; j < 4; ++j) {
      p1[i][j] = (double)P1f[n * 12 + i * 4 + j];
      p2[i][j] = (double)P2f[n * 12 + i * 4 + j];
    }
  double A[3][3];
  for (int i = 0; i < 3; ++i)
    for (int j = 0; j < 3; ++j) {
      double s = 0;
      for (int k = 0; k < 4; ++k) s += p1[i][k] * p1[j][k];
      A[i][j] = s;
    }
  double det = A[0][0] * (A[1][1] * A[2][2] - A[1][2] * A[2][1])
             - A[0][1] * (A[1][0] * A[2][2] - A[1][2] * A[2][0])
             + A[0][2] * (A[1][0] * A[2][1] - A[1][1] * A[2][0]);
  double id = 1.0 / det;
  double Ai[3][3];
  Ai[0][0] = (A[1][1] * A[2][2] - A[1][2] * A[2][1]) * id;
  Ai[0][1] = (A[0][2] * A[2][1] - A[0][1] * A[2][2]) * id;
  Ai[0][2] = (A[0][1] * A[1][2] - A[0][2] * A[1][1]) * id;
  Ai[1][0] = (A[1][2] * A[2][0] - A[1][0] * A[2][2]) * id;
  Ai[1][1] = (A[0][0] * A[2][2] - A[0][2] * A[2][0]) * id;
  Ai[1][2] = (A[0][2] * A[1][0] - A[0][0] * A[1][2]) * id;
  Ai[2][0] = (A[1][0] * A[2][1] - A[1][1] * A[2][0]) * id;
  Ai[2][1] = (A[0][1] * A[2][0] - A[0][0] * A[2][1]) * id;
  Ai[2][2] = (A[0][0] * A[1][1] - A[0][1] * A[1][0]) * id;
  double Pi[4][3];
  for (int i = 0; i < 4; ++i)
    for (int j = 0; j < 3; ++j) {
      double s = 0;
      for (int k = 0; k < 3; ++k) s += p1[k][i] * Ai[k][j];
      Pi[i][j] = s;
    }
  double M[3][3];
  for (int i = 0; i < 3; ++i)
    for (int j = 0; j < 3; ++j) {
      double s = 0;
      for (int k = 0; k < 4; ++k) s += p2[i][k] * Pi[k][j];
      M[i][j] = s;
    }
  double nv[4];
  {
    auto det3 = [&](int ca, int cb, int cc) {
      return p1[0][ca] * (p1[1][cb] * p1[2][cc] - p1[1][cc] * p1[2][cb])
           - p1[0][cb] * (p1[1][ca] * p1[2][cc] - p1[1][cc] * p1[2][ca])
           + p1[0][cc] * (p1[1][ca] * p1[2][cb] - p1[1][cb] * p1[2][ca]);
    };
    nv[0] =  det3(1, 2, 3);
    nv[1] = -det3(0, 2, 3);
    nv[2] =  det3(0, 1, 3);
    nv[3] = -det3(0, 1, 2);
  }
  double nn = sqrt(nv[0]*nv[0] + nv[1]*nv[1] + nv[2]*nv[2] + nv[3]*nv[3]);
  for (int i = 0; i < 4; ++i) nv[i] /= nn;
  double e2[3];
  for (int i = 0; i < 3; ++i) {
    double s = 0;
    for (int j = 0; j < 4; ++j) s += p2[i][j] * nv[j];
    e2[i] = s;
  }
  for (int j = 0; j < 3; ++j) {
    Fout[n * 9 + 0 * 3 + j] = -e2[2] * M[1][j] + e2[1] * M[2][j];
    Fout[n * 9 + 1 * 3 + j] =  e2[2] * M[0][j] - e2[0] * M[2][j];
    Fout[n * 9 + 2 * 3 + j] = -e2[1] * M[0][j] + e2[0] * M[1][j];
  }
}

// ---- Kernel 1: feat2 [N,C,H,W] -> f2t fp16 [N,HW,C]; fused fmat ------------
__global__ __launch_bounds__(256) void prep_kernel(
    const float* __restrict__ feat2,
    const float* __restrict__ P1f, const float* __restrict__ P2f,
    _Float16* __restrict__ f2t, double* __restrict__ Fd) {
  __shared__ float tile[32][33];
  const int n  = blockIdx.z;
  const int p0 = blockIdx.x * 32;
  const int c0 = blockIdx.y * 32;
  const int tx = threadIdx.x, ty = threadIdx.y;   // block (32,8)
  const float* src = feat2 + (size_t)n * (C * HW);
#pragma unroll
  for (int j = 0; j < 4; ++j) {
    int cc = c0 + ty + j * 8;
    tile[ty + j * 8][tx] = src[(size_t)cc * HW + p0 + tx];
  }
  __syncthreads();
  {
    const int tid = ty * 32 + tx;
    const int pp = tid >> 3;        // 0..31
    const int cp = tid & 7;         // 0..7
    _Float16* dst = f2t + (size_t)n * (HW * C) + (size_t)(p0 + pp) * C + c0;
#pragma unroll
    for (int jj = 0; jj < 2; ++jj) {
      const int cc = (cp + jj * 8) * 2;          // 0,2,..,30
      half2v h2;
      h2.x = (_Float16)tile[cc][pp];
      h2.y = (_Float16)tile[cc + 1][pp];
      *(half2v*)(dst + cc) = h2;
    }
  }
  if (n == 0 && blockIdx.x == 0 && blockIdx.y == 0) {
    int t = ty * 32 + tx;
    if (t < NB) fmat_compute(P1f, P2f, Fd, t);
  }
}

// ---- 64-lane sum: 4 DPP steps + shfl_xor(16) + shfl_xor(32) ----------------
// (all primitives verified in passing rounds R1-R16)
__device__ __forceinline__ float wavesum64(float v) {
  v += __int_as_float(__builtin_amdgcn_update_dpp(
         0, __float_as_int(v), 0xB1, 0xF, 0xF, true));   // quad_perm xor1
  v += __int_as_float(__builtin_amdgcn_update_dpp(
         0, __float_as_int(v), 0x4E, 0xF, 0xF, true));   // quad_perm xor2
  v += __int_as_float(__builtin_amdgcn_update_dpp(
         0, __float_as_int(v), 0x124, 0xF, 0xF, true));  // row_ror:4
  v += __int_as_float(__builtin_amdgcn_update_dpp(
         0, __float_as_int(v), 0x128, 0xF, 0xF, true));  // row_ror:8
  v += __shfl_xor(v, 16);
  v += __shfl_xor(v, 32);
  return v;
}

// ---- Kernel 2: 1 px/wave, 64 lanes span contiguous 1KB corner-PAIR loads ---
// Lanes 0-31 = corner col bc, lanes 32-63 = col bc+1 (adjacent 512B blocks):
// every gather is ONE contiguous 1KB wave64 dwordx4 load (fast TA path).
// L1 row base clamped to H-1 (its weights are provably 0 when clamped), so
// ALL loads stay inside f2t -- no pad needed. Weight folding via cndmask
// reproduces the reference's clamp+mask gather semantics exactly.
__global__ __launch_bounds__(256) void epi_main(
    const float* __restrict__ feat1, const _Float16* __restrict__ f2t,
    const double* __restrict__ Fd, float* __restrict__ out) {
  const int tid  = threadIdx.x;
  const int lane = tid & 63;
  const int wv   = tid >> 6;
  const bool halfB = lane >= 32;            // corner column half
  const int cl   = lane & 31;
  const int bid  = blockIdx.x;
  const int r    = bid & 7;
  const int k    = bid >> 3;                // 0..255
  const int n    = r >> 2;
  const int sub  = r & 3;                   // row stripe (1024 px)
  const int p    = sub * 1024 + k * 4 + wv;
  const int h = p >> 6, w = p & (W - 1);
  const int cb = cl * 8;                    // channel base for this lane

  // --- f1: 8 channels cb..cb+7 (both halves load same -> broadcast) ---
  half2v f1h[4];
  {
    const float* f1b = feat1 + ((size_t)n * C + cb) * HW + p;
#pragma unroll
    for (int i = 0; i < 4; ++i) {
      const float lo = f1b[(size_t)(2 * i) * HW];
      const float hi = f1b[(size_t)(2 * i + 1) * HW];
      f1h[i] = __builtin_bit_cast(half2v, __builtin_amdgcn_cvt_pkrtz(lo, hi));
    }
  }

  // --- epipolar line + endpoint pick, fp32 ---
  const double* Fdp = Fd + n * 9;
  const float F0 = (float)Fdp[0], F1 = (float)Fdp[1], F2 = (float)Fdp[2];
  const float F3 = (float)Fdp[3], F4 = (float)Fdp[4], F5 = (float)Fdp[5];
  const float F6 = (float)Fdp[6], F7 = (float)Fdp[7], F8 = (float)Fdp[8];
  const float X = w * 4.0f + 1.5f;
  const float Y = h * 4.0f + 1.5f;
  const float a = F0 * X + F1 * Y + F2;
  const float b = F3 * X + F4 * Y + F5;
  const float c = F6 * X + F7 * Y + F8;
  const float a_s = (fabsf(a) < 1e-3f) ? 1e-3f : a;
  const float b_s = (fabsf(b) < 1e-3f) ? 1e-3f : b;
  const float xmin = 1.5f, xmax = 253.5f, ymin = 1.5f, ymax = 253.5f, tol = 0.01f;
  float cx[4], cy[4];
  cx[0] = xmin;  cy[0] = -(c + a * xmin) / b_s;
  cx[1] = xmax;  cy[1] = -(c + a * xmax) / b_s;
  cx[2] = -(c + b * ymin) / a_s;  cy[2] = ymin;
  cx[3] = -(c + b * ymax) / a_s;  cy[3] = ymax;
  bool valid[4];
#pragma unroll
  for (int i = 0; i < 4; ++i)
    valid[i] = (cx[i] >= xmin - tol) && (cx[i] <= xmax + tol) &&
               (cy[i] >= ymin - tol) && (cy[i] <= ymax + tol);
#pragma unroll
  for (int i = 0; i < 4; ++i)
    if (!valid[i]) { cx[i] = xmin - 10000.0f; cy[i] = ymin - 10000.0f; }
  int pk0 = -1, pk1 = -1;
#pragma unroll
  for (int i = 0; i < 4; ++i)
    if (valid[i]) { if (pk0 < 0) pk0 = i; else if (pk1 < 0) pk1 = i; }
#pragma unroll
  for (int i = 0; i < 4; ++i)
    if (!valid[i]) { if (pk0 < 0) pk0 = i; else if (pk1 < 0) pk1 = i; }
  const float x0p = (cx[pk0] - 1.5f) * 0.25f;
  const float y0p = (cy[pk0] - 1.5f) * 0.25f;
  const float pdx = (cx[pk1] - 1.5f) * 0.25f - x0p;
  const float pdy = (cy[pk1] - 1.5f) * 0.25f - y0p;
  const float dx = pdx * (1.0f / 31.0f);
  const float dy = pdy * (1.0f / 31.0f);

  const _Float16* f2i = f2t + (size_t)n * HW * C + lane * 8;

  float m = -1e30f, l = 0.f;
  half2v acc2[4];
#pragma unroll
  for (int i = 0; i < 4; ++i) acc2[i] = (half2v)(_Float16)0;

  // fetch sample at (x,y): two contiguous 1KB row loads + folded weights
  auto fetch = [&](float x, float y, uint4& L0, uint4& L1,
                   float& w0f, float& w1f) {
    const float xf = floorf(x), yf = floorf(y);
    const float wx = x - xf, wy = y - yf;
    const int x0 = (int)xf, y0 = (int)yf;
    const bool bx0 = ((unsigned)x0 < W), bx1 = ((unsigned)(x0 + 1) < W);
    const bool by0 = ((unsigned)y0 < H), by1 = ((unsigned)(y0 + 1) < H);
    const int bc = min(max(x0, 0), W - 1);
    const int br = min(max(y0, 0), H - 1);
    const float ux0 = bx0 ? (1.f - wx) : 0.f;
    const float ux1 = bx1 ? wx : 0.f;
    const float vy0 = by0 ? (1.f - wy) : 0.f;
    const float vy1 = by1 ? wy : 0.f;
    const float w00 = vy0 * ux0, w01 = vy0 * ux1;
    const float w10 = vy1 * ux0, w11 = vy1 * ux1;
    // row fold: slot-row br semantics (y0<0 -> br==y1, row-y0 weights are 0)
    const bool yneg = (y0 < 0);
    const float ra0 = yneg ? w10 : w00, ra1 = yneg ? w11 : w01;
    const float rb0 = yneg ? 0.f : w10, rb1 = yneg ? 0.f : w11;
    // col fold: slot-col bc semantics (x0<0 -> bc==x1, col-x0 weights are 0)
    const bool xneg = (x0 < 0);
    const float sa = xneg ? ra1 : ra0, sb = xneg ? 0.f : ra1;
    const float ta = xneg ? rb1 : rb0, tb = xneg ? 0.f : rb1;
    w0f = halfB ? sb : sa;                  // weight for L0 (row br)
    w1f = halfB ? tb : ta;                  // weight for L1 (row br2)
    const int br2 = min(br + 1, H - 1);     // clamped: w1f==0 when clamped
    L0 = *(const uint4*)(f2i + (size_t)(br  * W + bc) * C);
    L1 = *(const uint4*)(f2i + (size_t)(br2 * W + bc) * C);
  };

  auto dots = [&](const uint4& L0, const uint4& L1, float& d0, float& d1) {
    const uint* p0w = (const uint*)&L0;
    const uint* p1w = (const uint*)&L1;
    d0 = 0.f; d1 = 0.f;
#pragma unroll
    for (int j = 0; j < 4; ++j) {
      d0 = fdot2(__builtin_bit_cast(half2v, p0w[j]), f1h[j], d0);
      d1 = fdot2(__builtin_bit_cast(half2v, p1w[j]), f1h[j], d1);
    }
  };

  // pairwise loop: 2 independent samples per iteration, joint softmax
  float xs = x0p, ys = y0p;
#pragma unroll
  for (int s = 0; s < SS; s += 2) {
    uint4 A0, A1, B0, B1;
    float wa0, wa1, wb0, wb1;
    fetch(xs,      ys,      A0, A1, wa0, wa1);
    fetch(xs + dx, ys + dy, B0, B1, wb0, wb1);
    xs += 2.f * dx;
    ys += 2.f * dy;

    float da0, da1, db0, db1;
    dots(A0, A1, da0, da1);
    dots(B0, B1, db0, db1);
    float p0 = wavesum64(fmaf(wa0, da0, wa1 * da1));
    float p1 = wavesum64(fmaf(wb0, db0, wb1 * db1));

    const float mx = fmaxf(p0, p1);
    if (__any(mx > m + 4.f)) {            // defer-max (T=4, f16-safe acc)
      const float mn = fmaxf(m, mx);
      const float sc = __expf(m - mn);
      l *= sc;
      const half2v sch = pk2(sc);
#pragma unroll
      for (int i = 0; i < 4; ++i) acc2[i] *= sch;
      m = mn;
    }
    const float e0 = __expf(p0 - m);
    const float e1 = __expf(p1 - m);
    l += e0 + e1;
    const half2v eh0 = pk2(e0), eh1 = pk2(e1);
    const half2v wA0 = pk2(wa0), wA1 = pk2(wa1);
    const half2v wB0 = pk2(wb0), wB1 = pk2(wb1);
    const uint* a0w = (const uint*)&A0;
    const uint* a1w = (const uint*)&A1;
    const uint* b0w = (const uint*)&B0;
    const uint* b1w = (const uint*)&B1;
#pragma unroll
    for (int i = 0; i < 4; ++i) {
      half2v q0 = __builtin_bit_cast(half2v, a0w[i]) * wA0 +
                  __builtin_bit_cast(half2v, a1w[i]) * wA1;
      half2v q1 = __builtin_bit_cast(half2v, b0w[i]) * wB0 +
                  __builtin_bit_cast(half2v, b1w[i]) * wB1;
      acc2[i] += eh0 * q0;
      acc2[i] += eh1 * q1;
    }
  }

  // merge corner halves: ch value = lane(l) + lane(l^32)
#pragma unroll
  for (int i = 0; i < 4; ++i) {
    const int sw = __shfl_xor(__builtin_bit_cast(int, acc2[i]), 32);
    acc2[i] = acc2[i] + __builtin_bit_cast(half2v, sw);
  }

  const float inv = 1.0f / l;
  if (!halfB) {
    float* ob = out + (size_t)n * C * HW + (size_t)cb * HW + p;
#pragma unroll
    for (int i = 0; i < 4; ++i) {
      ob[(size_t)(2 * i) * HW]     = (float)acc2[i].x * inv;
      ob[(size_t)(2 * i + 1) * HW] = (float)acc2[i].y * inv;
    }
  }
}

extern "C" void kernel_launch(void* const* d_in, const int* in_sizes, int n_in,
                              void* d_out, int out_size, void* d_ws, size_t ws_size,
                              hipStream_t stream) {
  const float* feat1 = (const float*)d_in[0];
  const float* feat2 = (const float*)d_in[1];
  const float* P1 = (const float*)d_in[2];
  const float* P2 = (const float*)d_in[3];
  float* out = (float*)d_out;

  char* ws = (char*)d_ws;
  _Float16* f2t = (_Float16*)ws;                            // 4 MB @ 0
  double*   Fd  = (double*)(ws + (5u << 20));               // @ 5 MB

  prep_kernel<<<dim3(HW / 32, C / 32, NB), dim3(32, 8), 0, stream>>>(
      feat2, P1, P2, f2t, Fd);
  epi_main<<<NB * HW / 4, 256, 0, stream>>>(feat1, f2t, Fd, out);
}

// Round 19
// 40.843 us; speedup vs baseline: 1.3445x; 1.3445x over previous
//
#include <hip/hip_runtime.h>
#include <math.h>

#define H 64
#define W 64
#define C 256
#define NB 2
#define SS 32
#define HW (H*W)

typedef __attribute__((ext_vector_type(2))) _Float16 half2v;
typedef __attribute__((ext_vector_type(2))) __fp16   fp16x2;

__device__ __forceinline__ half2v pk2(float a) {
  return __builtin_bit_cast(half2v, __builtin_amdgcn_cvt_pkrtz(a, a));
}

__device__ __forceinline__ float fdot2(half2v a, half2v b, float c) {
#if __has_builtin(__builtin_amdgcn_fdot2)
  return __builtin_amdgcn_fdot2(__builtin_bit_cast(fp16x2, a),
                                __builtin_bit_cast(fp16x2, b), c, false);
#else
  c = fmaf((float)a.x, (float)b.x, c);
  c = fmaf((float)a.y, (float)b.y, c);
  return c;
#endif
}

// ---- fmat body (fp64) ----
__device__ void fmat_compute(const float* __restrict__ P1f,
                             const float* __restrict__ P2f,
                             double* __restrict__ Fout, int n) {
  double p1[3][4], p2[3][4];
  for (int i = 0; i < 3; ++i)
    for (int j = 0; j < 4; ++j) {
      p1[i][j] = (double)P1f[n * 12 + i * 4 + j];
      p2[i][j] = (double)P2f[n * 12 + i * 4 + j];
    }
  double A[3][3];
  for (int i = 0; i < 3; ++i)
    for (int j = 0; j < 3; ++j) {
      double s = 0;
      for (int k = 0; k < 4; ++k) s += p1[i][k] * p1[j][k];
      A[i][j] = s;
    }
  double det = A[0][0] * (A[1][1] * A[2][2] - A[1][2] * A[2][1])
             - A[0][1] * (A[1][0] * A[2][2] - A[1][2] * A[2][0])
             + A[0][2] * (A[1][0] * A[2][1] - A[1][1] * A[2][0]);
  double id = 1.0 / det;
  double Ai[3][3];
  Ai[0][0] = (A[1][1] * A[2][2] - A[1][2] * A[2][1]) * id;
  Ai[0][1] = (A[0][2] * A[2][1] - A[0][1] * A[2][2]) * id;
  Ai[0][2] = (A[0][1] * A[1][2] - A[0][2] * A[1][1]) * id;
  Ai[1][0] = (A[1][2] * A[2][0] - A[1][0] * A[2][2]) * id;
  Ai[1][1] = (A[0][0] * A[2][2] - A[0][2] * A[2][0]) * id;
  Ai[1][2] = (A[0][2] * A[1][0] - A[0][0] * A[1][2]) * id;
  Ai[2][0] = (A[1][0] * A[2][1] - A[1][1] * A[2][0]) * id;
  Ai[2][1] = (A[0][1] * A[2][0] - A[0][0] * A[2][1]) * id;
  Ai[2][2] = (A[0][0] * A[1][1] - A[0][1] * A[1][0]) * id;
  double Pi[4][3];
  for (int i = 0; i < 4; ++i)
    for (int j = 0; j < 3; ++j) {
      double s = 0;
      for (int k = 0; k < 3; ++k) s += p1[k][i] * Ai[k][j];
      Pi[i][j] = s;
    }
  double M[3][3];
  for (int i = 0; i < 3; ++i)
    for (int j = 0; j < 3; ++j) {
      double s = 0;
      for (int k = 0; k < 4; ++k) s += p2[i][k] * Pi[k][j];
      M[i][j] = s;
    }
  double nv[4];
  {
    auto det3 = [&](int ca, int cb, int cc) {
      return p1[0][ca] * (p1[1][cb] * p1[2][cc] - p1[1][cc] * p1[2][cb])
           - p1[0][cb] * (p1[1][ca] * p1[2][cc] - p1[1][cc] * p1[2][ca])
           + p1[0][cc] * (p1[1][ca] * p1[2][cb] - p1[1][cb] * p1[2][ca]);
    };
    nv[0] =  det3(1, 2, 3);
    nv[1] = -det3(0, 2, 3);
    nv[2] =  det3(0, 1, 3);
    nv[3] = -det3(0, 1, 2);
  }
  double nn = sqrt(nv[0]*nv[0] + nv[1]*nv[1] + nv[2]*nv[2] + nv[3]*nv[3]);
  for (int i = 0; i < 4; ++i) nv[i] /= nn;
  double e2[3];
  for (int i = 0; i < 3; ++i) {
    double s = 0;
    for (int j = 0; j < 4; ++j) s += p2[i][j] * nv[j];
    e2[i] = s;
  }
  for (int j = 0; j < 3; ++j) {
    Fout[n * 9 + 0 * 3 + j] = -e2[2] * M[1][j] + e2[1] * M[2][j];
    Fout[n * 9 + 1 * 3 + j] =  e2[2] * M[0][j] - e2[0] * M[2][j];
    Fout[n * 9 + 2 * 3 + j] = -e2[1] * M[0][j] + e2[0] * M[1][j];
  }
}

// ---- Kernel 1: feat2 [N,C,H,W] -> f2t fp16 [N,HW,C]; fused fmat ------------
__global__ __launch_bounds__(256) void prep_kernel(
    const float* __restrict__ feat2,
    const float* __restrict__ P1f, const float* __restrict__ P2f,
    _Float16* __restrict__ f2t, double* __restrict__ Fd) {
  __shared__ float tile[32][33];
  const int n  = blockIdx.z;
  const int p0 = blockIdx.x * 32;
  const int c0 = blockIdx.y * 32;
  const int tx = threadIdx.x, ty = threadIdx.y;   // block (32,8)
  const float* src = feat2 + (size_t)n * (C * HW);
#pragma unroll
  for (int j = 0; j < 4; ++j) {
    int cc = c0 + ty + j * 8;
    tile[ty + j * 8][tx] = src[(size_t)cc * HW + p0 + tx];
  }
  __syncthreads();
  {
    const int tid = ty * 32 + tx;
    const int pp = tid >> 3;        // 0..31
    const int cp = tid & 7;         // 0..7
    _Float16* dst = f2t + (size_t)n * (HW * C) + (size_t)(p0 + pp) * C + c0;
#pragma unroll
    for (int jj = 0; jj < 2; ++jj) {
      const int cc = (cp + jj * 8) * 2;          // 0,2,..,30
      half2v h2;
      h2.x = (_Float16)tile[cc][pp];
      h2.y = (_Float16)tile[cc + 1][pp];
      *(half2v*)(dst + cc) = h2;
    }
  }
  if (n == 0 && blockIdx.x == 0 && blockIdx.y == 0) {
    int t = ty * 32 + tx;
    if (t < NB) fmat_compute(P1f, P2f, Fd, t);
  }
}

// ---- 32-lane-group sum, pure VALU (verified R16) ----------------------------
__device__ __forceinline__ float groupsum32(float v) {
  v += __int_as_float(__builtin_amdgcn_update_dpp(
         0, __float_as_int(v), 0xB1, 0xF, 0xF, true));   // quad_perm xor1
  v += __int_as_float(__builtin_amdgcn_update_dpp(
         0, __float_as_int(v), 0x4E, 0xF, 0xF, true));   // quad_perm xor2
  v += __int_as_float(__builtin_amdgcn_update_dpp(
         0, __float_as_int(v), 0x124, 0xF, 0xF, true));  // row_ror:4
  v += __int_as_float(__builtin_amdgcn_update_dpp(
         0, __float_as_int(v), 0x128, 0xF, 0xF, true));  // row_ror:8
#if __has_builtin(__builtin_amdgcn_permlane16_swap)
  {
    auto pr = __builtin_amdgcn_permlane16_swap(
        __float_as_int(v), __float_as_int(v), false, false);
    v = __int_as_float(pr[0]) + __int_as_float(pr[1]);
  }
#else
  v += __int_as_float(__builtin_amdgcn_ds_swizzle(
         __float_as_int(v), 0x401F));                    // xor16 (LDS pipe)
#endif
  return v;
}

// ---- Kernel 2: 2 px/block, 32 lanes/px, 8 ch/lane, 2-wave S-split ----------
// R16's lean packed-f16 body; wave sh handles samples [sh*16, sh*16+16);
// exact online-softmax merge via LDS (R3/R10-verified pattern).
__global__ __launch_bounds__(128) void epi_main(
    const float* __restrict__ feat1, const _Float16* __restrict__ f2t,
    const double* __restrict__ Fd, float* __restrict__ out) {
  const int tid  = threadIdx.x;
  const int lane = tid & 63;
  const int sh   = tid >> 6;                // S-half (0/1)
  const int grp  = lane >> 5;               // pixel within block (0/1)
  const int cl   = lane & 31;               // channel lane
  const int bid  = blockIdx.x;
  const int r    = bid & 7;
  const int k    = bid >> 3;                // 0..511
  const int n    = r >> 2;
  const int sub  = r & 3;                   // row stripe (1024 px)
  const int p    = sub * 1024 + k * 2 + grp;
  const int h = p >> 6, w = p & (W - 1);
  const int cb = cl * 8;                    // channel base for this lane

  // --- f1: 8 channels cb..cb+7, packed to 4x half2 for v_dot2 ---
  half2v f1h[4];
  {
    const float* f1b = feat1 + ((size_t)n * C + cb) * HW + p;
#pragma unroll
    for (int i = 0; i < 4; ++i) {
      const float lo = f1b[(size_t)(2 * i) * HW];
      const float hi = f1b[(size_t)(2 * i + 1) * HW];
      f1h[i] = __builtin_bit_cast(half2v, __builtin_amdgcn_cvt_pkrtz(lo, hi));
    }
  }

  // --- epipolar line + endpoint pick, fp32 ---
  const double* Fdp = Fd + n * 9;
  const float F0 = (float)Fdp[0], F1 = (float)Fdp[1], F2 = (float)Fdp[2];
  const float F3 = (float)Fdp[3], F4 = (float)Fdp[4], F5 = (float)Fdp[5];
  const float F6 = (float)Fdp[6], F7 = (float)Fdp[7], F8 = (float)Fdp[8];
  const float X = w * 4.0f + 1.5f;
  const float Y = h * 4.0f + 1.5f;
  const float a = F0 * X + F1 * Y + F2;
  const float b = F3 * X + F4 * Y + F5;
  const float c = F6 * X + F7 * Y + F8;
  const float a_s = (fabsf(a) < 1e-3f) ? 1e-3f : a;
  const float b_s = (fabsf(b) < 1e-3f) ? 1e-3f : b;
  const float xmin = 1.5f, xmax = 253.5f, ymin = 1.5f, ymax = 253.5f, tol = 0.01f;
  float cx[4], cy[4];
  cx[0] = xmin;  cy[0] = -(c + a * xmin) / b_s;
  cx[1] = xmax;  cy[1] = -(c + a * xmax) / b_s;
  cx[2] = -(c + b * ymin) / a_s;  cy[2] = ymin;
  cx[3] = -(c + b * ymax) / a_s;  cy[3] = ymax;
  bool valid[4];
#pragma unroll
  for (int i = 0; i < 4; ++i)
    valid[i] = (cx[i] >= xmin - tol) && (cx[i] <= xmax + tol) &&
               (cy[i] >= ymin - tol) && (cy[i] <= ymax + tol);
#pragma unroll
  for (int i = 0; i < 4; ++i)
    if (!valid[i]) { cx[i] = xmin - 10000.0f; cy[i] = ymin - 10000.0f; }
  int pk0 = -1, pk1 = -1;
#pragma unroll
  for (int i = 0; i < 4; ++i)
    if (valid[i]) { if (pk0 < 0) pk0 = i; else if (pk1 < 0) pk1 = i; }
#pragma unroll
  for (int i = 0; i < 4; ++i)
    if (!valid[i]) { if (pk0 < 0) pk0 = i; else if (pk1 < 0) pk1 = i; }
  const float x0p = (cx[pk0] - 1.5f) * 0.25f;
  const float y0p = (cy[pk0] - 1.5f) * 0.25f;
  const float pdx = (cx[pk1] - 1.5f) * 0.25f - x0p;
  const float pdy = (cy[pk1] - 1.5f) * 0.25f - y0p;
  const float dx = pdx * (1.0f / 31.0f);
  const float dy = pdy * (1.0f / 31.0f);

  const _Float16* f2b = f2t + (size_t)n * HW * C + cb;

  float m = -1e30f, l = 0.f;
  half2v acc2[4];
#pragma unroll
  for (int i = 0; i < 4; ++i) acc2[i] = (half2v)(_Float16)0;

  auto fetch = [&](float x, float y, uint4& A, uint4& B, uint4& Cc, uint4& D,
                   half2v& wa, half2v& wb, half2v& wc, half2v& wd) {
    const float xf = floorf(x), yf = floorf(y);
    const float wx = x - xf, wy = y - yf;
    const int x0 = (int)xf, y0 = (int)yf;
    const bool bx0 = ((unsigned)x0 < W), bx1 = ((unsigned)(x0 + 1) < W);
    const bool by0 = ((unsigned)y0 < H), by1 = ((unsigned)(y0 + 1) < H);
    const int xc0 = min(max(x0, 0), W - 1);
    const int xc1 = min(max(x0 + 1, 0), W - 1);
    const int yc0 = min(max(y0, 0), H - 1);
    const int yc1 = min(max(y0 + 1, 0), H - 1);
    const float ux0 = bx0 ? (1.f - wx) : 0.f;
    const float ux1 = bx1 ? wx : 0.f;
    const float vy0 = by0 ? (1.f - wy) : 0.f;
    const float vy1 = by1 ? wy : 0.f;
    wa = pk2(vy0 * ux0);
    wb = pk2(vy0 * ux1);
    wc = pk2(vy1 * ux0);
    wd = pk2(vy1 * ux1);
    const int r0 = yc0 * W, r1 = yc1 * W;
    A  = *(const uint4*)(f2b + (r0 + xc0) * C);
    B  = *(const uint4*)(f2b + (r0 + xc1) * C);
    Cc = *(const uint4*)(f2b + (r1 + xc0) * C);
    D  = *(const uint4*)(f2b + (r1 + xc1) * C);
  };

  auto bilin = [&](const uint4& A, const uint4& B, const uint4& Cc,
                   const uint4& D, half2v wa, half2v wb, half2v wc, half2v wd,
                   half2v q[4], float& part) {
    const uint* ap = (const uint*)&A;
    const uint* bp = (const uint*)&B;
    const uint* cp = (const uint*)&Cc;
    const uint* dp = (const uint*)&D;
    part = 0.f;
#pragma unroll
    for (int j = 0; j < 4; ++j) {
      half2v qa = __builtin_bit_cast(half2v, ap[j]) * wa;
      qa += __builtin_bit_cast(half2v, bp[j]) * wb;
      qa += __builtin_bit_cast(half2v, cp[j]) * wc;
      qa += __builtin_bit_cast(half2v, dp[j]) * wd;
      q[j] = qa;
      part = fdot2(qa, f1h[j], part);
    }
  };

  // this wave's S-half: 16 samples, pairwise (2 independent per iteration)
  float xs = fmaf((float)(sh * 16), dx, x0p);
  float ys = fmaf((float)(sh * 16), dy, y0p);
#pragma unroll
  for (int s = 0; s < SS / 2; s += 2) {
    uint4 A0, B0, C0, D0, A1, B1, C1, D1;
    half2v wa0, wb0, wc0, wd0, wa1, wb1, wc1, wd1;
    fetch(xs,      ys,      A0, B0, C0, D0, wa0, wb0, wc0, wd0);
    fetch(xs + dx, ys + dy, A1, B1, C1, D1, wa1, wb1, wc1, wd1);
    xs += 2.f * dx;
    ys += 2.f * dy;

    half2v q0[4], q1[4];
    float p0, p1;
    bilin(A0, B0, C0, D0, wa0, wb0, wc0, wd0, q0, p0);
    bilin(A1, B1, C1, D1, wa1, wb1, wc1, wd1, q1, p1);
    p0 = groupsum32(p0);
    p1 = groupsum32(p1);

    const float mx = fmaxf(p0, p1);
    if (__any(mx > m + 4.f)) {            // defer-max (T=4, f16-safe acc)
      const float mn = fmaxf(m, mx);
      const float sc = __expf(m - mn);
      l *= sc;
      const half2v sch = pk2(sc);
#pragma unroll
      for (int i = 0; i < 4; ++i) acc2[i] *= sch;
      m = mn;
    }
    const float e0 = __expf(p0 - m);
    const float e1 = __expf(p1 - m);
    l += e0 + e1;
    const half2v eh0 = pk2(e0);
    const half2v eh1 = pk2(e1);
#pragma unroll
    for (int i = 0; i < 4; ++i) {
      acc2[i] += eh0 * q0[i];             // v_pk_fma_f16
      acc2[i] += eh1 * q1[i];
    }
  }

  // --- merge the two S-halves via LDS (exact online-softmax merge) ---
  __shared__ float lsm[64][8];
  if (sh) {
#pragma unroll
    for (int i = 0; i < 4; ++i)
      lsm[lane][i] = __int_as_float(__builtin_bit_cast(int, acc2[i]));
    lsm[lane][4] = m;
    lsm[lane][5] = l;
  }
  __syncthreads();
  if (!sh) {
    const float mo = lsm[lane][4], lo = lsm[lane][5];
    const float mf = fmaxf(m, mo);
    const float e0 = __expf(m - mf), e1 = __expf(mo - mf);
    const float L = l * e0 + lo * e1;
    const float inv = 1.0f / L;
    const half2v eh0 = pk2(e0), eh1 = pk2(e1);
    float* ob = out + (size_t)n * C * HW + (size_t)cb * HW + p;
#pragma unroll
    for (int i = 0; i < 4; ++i) {
      const half2v bo = __builtin_bit_cast(half2v,
                          __float_as_int(lsm[lane][i]));
      const half2v merged = acc2[i] * eh0 + bo * eh1;
      ob[(size_t)(2 * i) * HW]     = (float)merged.x * inv;
      ob[(size_t)(2 * i + 1) * HW] = (float)merged.y * inv;
    }
  }
}

extern "C" void kernel_launch(void* const* d_in, const int* in_sizes, int n_in,
                              void* d_out, int out_size, void* d_ws, size_t ws_size,
                              hipStream_t stream) {
  const float* feat1 = (const float*)d_in[0];
  const float* feat2 = (const float*)d_in[1];
  const float* P1 = (const float*)d_in[2];
  const float* P2 = (const float*)d_in[3];
  float* out = (float*)d_out;

  char* ws = (char*)d_ws;
  _Float16* f2t = (_Float16*)ws;                            // 4 MB @ 0
  double*   Fd  = (double*)(ws + (5u << 20));               // @ 5 MB

  prep_kernel<<<dim3(HW / 32, C / 32, NB), dim3(32, 8), 0, stream>>>(
      feat2, P1, P2, f2t, Fd);
  epi_main<<<NB * HW / 2, 128, 0, stream>>>(feat1, f2t, Fd, out);
}